// Round 1
// baseline (25867.041 us; speedup 1.0000x reference)
//
#include <hip/hip_runtime.h>
#include <cstdint>
#include <cstddef>

#define T_SEQ 1024
#define BATCH 64
#define NH 2048
// NINP == 2048 as well

typedef _Float16 half8 __attribute__((ext_vector_type(8)));
typedef _Float16 half4 __attribute__((ext_vector_type(4)));
typedef float f32x4 __attribute__((ext_vector_type(4)));

__device__ inline void gload_lds16(const void* g, void* l) {
    __builtin_amdgcn_global_load_lds(
        (const __attribute__((address_space(1))) uint32_t*)g,
        (__attribute__((address_space(3))) uint32_t*)l,
        16, 0, 0);
}

// ---------------- fp32 -> fp16 conversion (vectorized, n % 4 == 0) ----------
__global__ __launch_bounds__(256) void cvt_f32_f16(const float* __restrict__ src,
                                                   _Float16* __restrict__ dst,
                                                   long long n) {
    long long i = ((long long)blockIdx.x * 256 + threadIdx.x) * 4;
    long long stride = (long long)gridDim.x * 256 * 4;
    for (; i < n; i += stride) {
        const float4 v = *(const float4*)(src + i);
        half4 o;
        o[0] = (_Float16)v.x; o[1] = (_Float16)v.y;
        o[2] = (_Float16)v.z; o[3] = (_Float16)v.w;
        *(half4*)(dst + i) = o;
    }
}

// ---------------- projection GEMM: C[m][n] = sum_k A[m][k] * B[n][k] --------
// A: [M][2048] fp16, B: [6144][2048] fp16 (Wcx|Wix|Wfx rows), C: [M][6144] fp16
// m97-style 128x128 tile, BK=64, 4 waves, global_load_lds width 16.
__global__ __launch_bounds__(256) void proj_gemm(const _Float16* __restrict__ A,
                                                 const _Float16* __restrict__ B,
                                                 _Float16* __restrict__ C, int M) {
    __shared__ _Float16 As[128][64];
    __shared__ _Float16 Bs[128][64];
    const int NBN = 48;                 // 6144 / 128
    const int nbm = M >> 7;
    const int nwg = nbm * NBN;          // divisible by 8 (M >= 2048)
    const int per = nwg >> 3;
    const int bid = blockIdx.x;
    const int swz = (bid & 7) * per + (bid >> 3);   // XCD-aware swizzle (bijective)
    const int bm = swz / NBN, bn = swz % NBN;

    const int tid = threadIdx.x;
    const int lane = tid & 63, w = tid >> 6;
    const int wm = w & 1, wn = w >> 1;

    f32x4 acc[4][4] = {};

    const int srow = lane >> 3;         // 0..7
    const int scol = (lane & 7) * 8;    // half units

    for (int bk = 0; bk < NH / 64; ++bk) {
#pragma unroll
        for (int i = 0; i < 4; ++i) {
            int r = w * 32 + i * 8;
            const _Float16* gA = A + (size_t)(bm * 128 + r + srow) * NH + bk * 64 + scol;
            gload_lds16(gA, &As[r][0]);
            const _Float16* gB = B + (size_t)(bn * 128 + r + srow) * NH + bk * 64 + scol;
            gload_lds16(gB, &Bs[r][0]);
        }
        __syncthreads();
#pragma unroll
        for (int kk = 0; kk < 2; ++kk) {
            half8 af[4], bf[4];
#pragma unroll
            for (int mi = 0; mi < 4; ++mi)
                af[mi] = *(const half8*)&As[wm * 64 + mi * 16 + (lane & 15)][kk * 32 + (lane >> 4) * 8];
#pragma unroll
            for (int ni = 0; ni < 4; ++ni)
                bf[ni] = *(const half8*)&Bs[wn * 64 + ni * 16 + (lane & 15)][kk * 32 + (lane >> 4) * 8];
#pragma unroll
            for (int mi = 0; mi < 4; ++mi)
#pragma unroll
                for (int ni = 0; ni < 4; ++ni)
                    acc[mi][ni] = __builtin_amdgcn_mfma_f32_16x16x32_f16(af[mi], bf[ni], acc[mi][ni], 0, 0, 0);
        }
        __syncthreads();
    }
#pragma unroll
    for (int mi = 0; mi < 4; ++mi)
#pragma unroll
        for (int ni = 0; ni < 4; ++ni)
#pragma unroll
            for (int r = 0; r < 4; ++r) {
                int m = bm * 128 + wm * 64 + mi * 16 + (lane >> 4) * 4 + r;
                int n = bn * 128 + wn * 64 + ni * 16 + (lane & 15);
                C[(size_t)m * 6144 + n] = (_Float16)acc[mi][ni][r];
            }
}

// ---------------- persistent scan kernel ------------------------------------
// 256 WGs x 512 threads, 1 WG/CU (LDS-forced). Each WG: b-group g (32 rows),
// j-slice of 16 columns. Weights (2 gates x 16j x 2048k fp16 = 128KB) live in
// LDS in MFMA B-fragment order for the whole kernel. Per step: GEMM
// M=32,N=32,K=2048 split over 8 waves (2 m-tiles x 4 k-quarters), LDS k-reduce,
// sigmoid/tanh epilogue on kq==0 waves, then device-wide counter barrier.
__global__ __launch_bounds__(512, 1) void scan_kernel(
    const _Float16* __restrict__ proj,   // [nsteps*64][6144] fp16 (c | ix | fx)
    const _Float16* __restrict__ Wr,     // [2][2048][2048] fp16 (W_ih, W_fh)
    _Float16* hb0, _Float16* hb1,        // [64][2048] fp16 ping-pong
    const float* __restrict__ b_i, const float* __restrict__ b_f,
    float* __restrict__ out,             // d_out: [1024][64][2048] + [64][2048]
    unsigned* cnt, int t0, int nsteps) {
    extern __shared__ char smem[];
    _Float16* Wlds = (_Float16*)smem;          // 131072 B
    float* red = (float*)(smem + 131072);      // 12288 B

    const int wg = blockIdx.x;
    const int g = (wg >> 3) & 1;                       // b-group (XCD-interleaved)
    const int idx = ((wg >> 4) << 3) | (wg & 7);       // 0..127 within group
    const int j0 = idx * 16;
    const int b0 = g * 32;

    const int tid = threadIdx.x;
    const int lane = tid & 63;
    const int w = tid >> 6;      // 8 waves
    const int mi = w & 1;        // m-tile (16 rows)
    const int kq = w >> 1;       // k-quarter (512 k)

    // One-time fill of LDS weight fragments:
    // fragment (gate, kk 0..63, lane l) = W[j0 + (l&15)][kk*32 + (l>>4)*8 .. +8]
    for (int q = 0; q < 16; ++q) {
        int e = q * 512 + tid;            // 0..8191
        int l = e & 63;
        int fk = (e >> 6) & 63;
        int gate = e >> 12;
        const _Float16* src = Wr + ((size_t)gate << 22) +
                              (size_t)(j0 + (l & 15)) * NH + fk * 32 + (l >> 4) * 8;
        *(half8*)(Wlds + ((size_t)(gate * 64 + fk) * 64 + l) * 8) = *(const half8*)src;
    }

    const float bi_s = b_i[j0 + (lane & 15)];
    const float bf_s = b_f[j0 + (lane & 15)];

    __syncthreads();

    for (int s = 0; s < nsteps; ++s) {
        const int t = t0 + s;
        const _Float16* hcur = (t & 1) ? hb1 : hb0;
        _Float16* hnxt = (t & 1) ? hb0 : hb1;

        // epilogue-input prefetch (only the waves that will do the epilogue)
        float pc[4], pix[4], pfx[4], ph[4];
        if (kq == 0) {
#pragma unroll
            for (int r = 0; r < 4; ++r) {
                int b = b0 + mi * 16 + (lane >> 4) * 4 + r;
                int j = j0 + (lane & 15);
                size_t pbase = ((size_t)s * 64 + b) * 6144 + j;
                pc[r] = (float)proj[pbase];
                pix[r] = (float)proj[pbase + 2048];
                pfx[r] = (float)proj[pbase + 4096];
                ph[r] = (float)hcur[(size_t)b * NH + j];
            }
        }

        // A fragments: this wave's 16 rows x 512-k quarter (16 x 16B loads)
        half8 afr[16];
        const _Float16* hrow = hcur + (size_t)(b0 + mi * 16 + (lane & 15)) * NH +
                               kq * 512 + (lane >> 4) * 8;
#pragma unroll
        for (int u = 0; u < 16; ++u) afr[u] = *(const half8*)(hrow + u * 32);

        f32x4 ai0 = {}, ai1 = {}, af0 = {}, af1 = {};
#pragma unroll
        for (int u = 0; u < 16; ++u) {
            int fk = kq * 16 + u;
            half8 wi = *(const half8*)(Wlds + ((size_t)fk * 64 + lane) * 8);
            half8 wf = *(const half8*)(Wlds + ((size_t)(64 + fk) * 64 + lane) * 8);
            if (u & 1) {
                ai1 = __builtin_amdgcn_mfma_f32_16x16x32_f16(afr[u], wi, ai1, 0, 0, 0);
                af1 = __builtin_amdgcn_mfma_f32_16x16x32_f16(afr[u], wf, af1, 0, 0, 0);
            } else {
                ai0 = __builtin_amdgcn_mfma_f32_16x16x32_f16(afr[u], wi, ai0, 0, 0, 0);
                af0 = __builtin_amdgcn_mfma_f32_16x16x32_f16(afr[u], wf, af0, 0, 0, 0);
            }
        }
        f32x4 acc_i = ai0 + ai1;
        f32x4 acc_f = af0 + af1;

        if (kq != 0) {
            f32x4* slot = (f32x4*)(red + ((size_t)(mi * 3 + (kq - 1)) * 64 + lane) * 8);
            slot[0] = acc_i;
            slot[1] = acc_f;
        }
        __syncthreads();

        if (kq == 0) {
#pragma unroll
            for (int p = 0; p < 3; ++p) {
                f32x4* slot = (f32x4*)(red + ((size_t)(mi * 3 + p) * 64 + lane) * 8);
                acc_i += slot[0];
                acc_f += slot[1];
            }
#pragma unroll
            for (int r = 0; r < 4; ++r) {
                int b = b0 + mi * 16 + (lane >> 4) * 4 + r;
                int j = j0 + (lane & 15);
                float iv = 1.0f / (1.0f + __expf(-(acc_i[r] + pix[r] + bi_s)));
                float fv = 1.0f / (1.0f + __expf(-(acc_f[r] + pfx[r] + bf_s)));
                float z = iv * pc[r] + fv * ph[r];
                float hn = 1.0f - 2.0f / (__expf(2.0f * z) + 1.0f);   // tanh(z)
                hnxt[(size_t)b * NH + j] = (_Float16)hn;
                out[(size_t)t * (BATCH * NH) + (size_t)b * NH + j] = hn;
                if (t == T_SEQ - 1)
                    out[(size_t)T_SEQ * (BATCH * NH) + (size_t)b * NH + j] = hn;
            }
        }
        __syncthreads();   // all stores drained to L2 (compiler vmcnt(0) before barrier)

        if (tid == 0) {
            __threadfence();   // agent fence: wbl2 -> stores visible at LLC
            __hip_atomic_fetch_add(cnt, 1u, __ATOMIC_RELEASE, __HIP_MEMORY_SCOPE_AGENT);
            const unsigned target = 256u * (unsigned)(t + 1);
            while (__hip_atomic_load(cnt, __ATOMIC_RELAXED, __HIP_MEMORY_SCOPE_AGENT) < target)
                __builtin_amdgcn_s_sleep(8);
            __builtin_amdgcn_fence(__ATOMIC_ACQUIRE, "agent");  // inv L1+L2
        }
        __syncthreads();
    }
}

// ---------------- host launch -----------------------------------------------
extern "C" void kernel_launch(void* const* d_in, const int* in_sizes, int n_in,
                              void* d_out, int out_size, void* d_ws, size_t ws_size,
                              hipStream_t stream) {
    const float* x = (const float*)d_in[0];
    const float* hidden = (const float*)d_in[1];
    const float* W_cx = (const float*)d_in[2];
    const float* W_ih = (const float*)d_in[3];
    const float* W_ix = (const float*)d_in[4];
    const float* W_fh = (const float*)d_in[5];
    const float* W_fx = (const float*)d_in[6];
    const float* b_i = (const float*)d_in[7];
    const float* b_f = (const float*)d_in[8];
    float* out = (float*)d_out;

    char* ws = (char*)d_ws;
    size_t off = 0;
    auto alloc = [&](size_t bytes) {
        char* p = ws + off;
        off += (bytes + 255) & ~(size_t)255;
        return p;
    };
    _Float16* Wp = (_Float16*)alloc((size_t)6144 * NH * 2);       // 24 MB
    _Float16* Wr = (_Float16*)alloc((size_t)2 * NH * NH * 2);     // 16 MB
    _Float16* hb0 = (_Float16*)alloc((size_t)BATCH * NH * 2);
    _Float16* hb1 = (_Float16*)alloc((size_t)BATCH * NH * 2);
    unsigned* cnt = (unsigned*)alloc(256);
    const size_t fixed = off;

    int chunk = 32;
    for (int c = T_SEQ; c >= 32; c >>= 1) {
        size_t need = fixed + (size_t)c * 64 * NH * 2 + (size_t)c * 64 * 6144 * 2 + 1024;
        if (need <= ws_size) { chunk = c; break; }
    }
    _Float16* xh = (_Float16*)alloc((size_t)chunk * 64 * NH * 2);
    _Float16* proj = (_Float16*)alloc((size_t)chunk * 64 * 6144 * 2);

    hipMemsetAsync(cnt, 0, 256, stream);

    const long long wsz = (long long)NH * NH;
    cvt_f32_f16<<<2048, 256, 0, stream>>>(W_cx, Wp, wsz);
    cvt_f32_f16<<<2048, 256, 0, stream>>>(W_ix, Wp + wsz, wsz);
    cvt_f32_f16<<<2048, 256, 0, stream>>>(W_fx, Wp + 2 * wsz, wsz);
    cvt_f32_f16<<<2048, 256, 0, stream>>>(W_ih, Wr, wsz);
    cvt_f32_f16<<<2048, 256, 0, stream>>>(W_fh, Wr + wsz, wsz);
    cvt_f32_f16<<<128, 256, 0, stream>>>(hidden, hb0, (long long)BATCH * NH);

    const int nch = T_SEQ / chunk;
    for (int c = 0; c < nch; ++c) {
        const int t0 = c * chunk;
        const int M = chunk * 64;
        cvt_f32_f16<<<2048, 256, 0, stream>>>(x + (size_t)t0 * 64 * NH, xh, (long long)M * NH);
        proj_gemm<<<dim3((M / 128) * 48), 256, 0, stream>>>(xh, Wp, proj, M);
        scan_kernel<<<256, 512, 143360, stream>>>(proj, Wr, hb0, hb1, b_i, b_f,
                                                  out, cnt, t0, chunk);
    }
}

// Round 2
// 13293.234 us; speedup vs baseline: 1.9459x; 1.9459x over previous
//
#include <hip/hip_runtime.h>
#include <cstdint>
#include <cstddef>

#define T_SEQ 1024
#define BATCH 64
#define NH 2048
// NINP == 2048 as well

typedef _Float16 half8 __attribute__((ext_vector_type(8)));
typedef _Float16 half4 __attribute__((ext_vector_type(4)));
typedef float f32x4 __attribute__((ext_vector_type(4)));

__device__ inline void gload_lds16(const void* g, void* l) {
    __builtin_amdgcn_global_load_lds(
        (const __attribute__((address_space(1))) uint32_t*)g,
        (__attribute__((address_space(3))) uint32_t*)l,
        16, 0, 0);
}

// LLC-bypass 16B load with compile-time byte offset (sc0 sc1: skip L1+L2,
// read at the coherence point = Infinity Cache).
#define LLC_LD16(dst, base, OFFSTR)                                         \
    asm volatile("global_load_dwordx4 %0, %1, off offset:" OFFSTR " sc0 sc1" \
                 : "=v"(dst) : "v"(base))

// LLC-bypass 2B store (write-through to the coherence point).
#define LLC_ST2(addr, val)                                                   \
    asm volatile("global_store_short %0, %1, off sc0 sc1"                    \
                 :: "v"(addr), "v"(val) : "memory")

__device__ inline void wait_vm0() {
    asm volatile("s_waitcnt vmcnt(0)" ::: "memory");
}

// ---------------- fp32 -> fp16 conversion (vectorized, n % 4 == 0) ----------
__global__ __launch_bounds__(256) void cvt_f32_f16(const float* __restrict__ src,
                                                   _Float16* __restrict__ dst,
                                                   long long n) {
    long long i = ((long long)blockIdx.x * 256 + threadIdx.x) * 4;
    long long stride = (long long)gridDim.x * 256 * 4;
    for (; i < n; i += stride) {
        const float4 v = *(const float4*)(src + i);
        half4 o;
        o[0] = (_Float16)v.x; o[1] = (_Float16)v.y;
        o[2] = (_Float16)v.z; o[3] = (_Float16)v.w;
        *(half4*)(dst + i) = o;
    }
}

// ---------------- projection GEMM: C[m][n] = sum_k A[m][k] * B[n][k] --------
// A: [M][2048] fp16, B: [6144][2048] fp16 (Wcx|Wix|Wfx rows), C: [M][6144] fp16
__global__ __launch_bounds__(256) void proj_gemm(const _Float16* __restrict__ A,
                                                 const _Float16* __restrict__ B,
                                                 _Float16* __restrict__ C, int M) {
    __shared__ _Float16 As[128][64];
    __shared__ _Float16 Bs[128][64];
    const int NBN = 48;                 // 6144 / 128
    const int nbm = M >> 7;
    const int nwg = nbm * NBN;          // divisible by 8 (M >= 2048)
    const int per = nwg >> 3;
    const int bid = blockIdx.x;
    const int swz = (bid & 7) * per + (bid >> 3);   // XCD-aware swizzle (bijective)
    const int bm = swz / NBN, bn = swz % NBN;

    const int tid = threadIdx.x;
    const int lane = tid & 63, w = tid >> 6;
    const int wm = w & 1, wn = w >> 1;

    f32x4 acc[4][4] = {};

    const int srow = lane >> 3;         // 0..7
    const int scol = (lane & 7) * 8;    // half units

    for (int bk = 0; bk < NH / 64; ++bk) {
#pragma unroll
        for (int i = 0; i < 4; ++i) {
            int r = w * 32 + i * 8;
            const _Float16* gA = A + (size_t)(bm * 128 + r + srow) * NH + bk * 64 + scol;
            gload_lds16(gA, &As[r][0]);
            const _Float16* gB = B + (size_t)(bn * 128 + r + srow) * NH + bk * 64 + scol;
            gload_lds16(gB, &Bs[r][0]);
        }
        __syncthreads();
#pragma unroll
        for (int kk = 0; kk < 2; ++kk) {
            half8 af[4], bf[4];
#pragma unroll
            for (int mi = 0; mi < 4; ++mi)
                af[mi] = *(const half8*)&As[wm * 64 + mi * 16 + (lane & 15)][kk * 32 + (lane >> 4) * 8];
#pragma unroll
            for (int ni = 0; ni < 4; ++ni)
                bf[ni] = *(const half8*)&Bs[wn * 64 + ni * 16 + (lane & 15)][kk * 32 + (lane >> 4) * 8];
#pragma unroll
            for (int mi = 0; mi < 4; ++mi)
#pragma unroll
                for (int ni = 0; ni < 4; ++ni)
                    acc[mi][ni] = __builtin_amdgcn_mfma_f32_16x16x32_f16(af[mi], bf[ni], acc[mi][ni], 0, 0, 0);
        }
        __syncthreads();
    }
#pragma unroll
    for (int mi = 0; mi < 4; ++mi)
#pragma unroll
        for (int ni = 0; ni < 4; ++ni)
#pragma unroll
            for (int r = 0; r < 4; ++r) {
                int m = bm * 128 + wm * 64 + mi * 16 + (lane >> 4) * 4 + r;
                int n = bn * 128 + wn * 64 + ni * 16 + (lane & 15);
                C[(size_t)m * 6144 + n] = (_Float16)acc[mi][ni][r];
            }
}

// ---------------- persistent scan kernel ------------------------------------
// 256 WGs x 512 threads, 1 WG/CU (LDS-forced). Each WG: b-group g (32 rows),
// j-slice of 16 columns. Weights (128KB) live in LDS in MFMA B-fragment order.
// Cross-step h exchange goes through the Infinity Cache (sc0 sc1 bypass ops);
// NO full-L2 writeback/invalidate anywhere in the loop. Two independent
// 128-WG counter barriers (one per b-group; rows are independent chains).
__global__ __launch_bounds__(512, 1) void scan_kernel(
    const _Float16* __restrict__ proj,   // [nsteps*64][6144] fp16 (c | ix | fx)
    const _Float16* __restrict__ Wr,     // [2][2048][2048] fp16 (W_ih, W_fh)
    _Float16* hb0, _Float16* hb1,        // [64][2048] fp16 ping-pong
    const float* __restrict__ b_i, const float* __restrict__ b_f,
    float* __restrict__ out,             // d_out: [1024][64][2048] + [64][2048]
    unsigned* cnt, int t0, int nsteps) {
    extern __shared__ char smem[];
    _Float16* Wlds = (_Float16*)smem;          // 131072 B
    float* red = (float*)(smem + 131072);      // 12288 B

    const int wg = blockIdx.x;
    const int g = (wg >> 3) & 1;                       // b-group (XCD-interleaved)
    const int idx = ((wg >> 4) << 3) | (wg & 7);       // 0..127 within group
    const int j0 = idx * 16;
    const int b0 = g * 32;
    unsigned* cnt_g = cnt + g * 32;                    // separate cache lines

    const int tid = threadIdx.x;
    const int lane = tid & 63;
    const int w = tid >> 6;      // 8 waves
    const int mi = w & 1;        // m-tile (16 rows)
    const int kq = w >> 1;       // k-quarter (512 k)

    // One-time fill of LDS weight fragments:
    // fragment (gate, kk 0..63, lane l) = W[j0 + (l&15)][kk*32 + (l>>4)*8 .. +8]
    for (int q = 0; q < 16; ++q) {
        int e = q * 512 + tid;            // 0..8191
        int l = e & 63;
        int fk = (e >> 6) & 63;
        int gate = e >> 12;
        const _Float16* src = Wr + ((size_t)gate << 22) +
                              (size_t)(j0 + (l & 15)) * NH + fk * 32 + (l >> 4) * 8;
        *(half8*)(Wlds + ((size_t)(gate * 64 + fk) * 64 + l) * 8) = *(const half8*)src;
    }

    const float bi_s = b_i[j0 + (lane & 15)];
    const float bf_s = b_f[j0 + (lane & 15)];

    // h[b][j] carry registers for the epilogue (this WG computed exactly these
    // (b,j) pairs last step; at dispatch start read them from the h buffer).
    float hprev[4];
    if (kq == 0) {
        const _Float16* hini = (t0 & 1) ? hb1 : hb0;
#pragma unroll
        for (int r = 0; r < 4; ++r) {
            int b = b0 + mi * 16 + (lane >> 4) * 4 + r;
            int j = j0 + (lane & 15);
            unsigned tmp;
            asm volatile("global_load_ushort %0, %1, off sc0 sc1\n\ts_waitcnt vmcnt(0)"
                         : "=v"(tmp) : "v"(hini + (size_t)b * NH + j));
            hprev[r] = (float)__builtin_bit_cast(_Float16, (unsigned short)tmp);
        }
    }

    __syncthreads();

    for (int s = 0; s < nsteps; ++s) {
        const int t = t0 + s;
        const _Float16* hcur = (t & 1) ? hb1 : hb0;
        _Float16* hnxt = (t & 1) ? hb0 : hb1;

        // epilogue-input prefetch (normal cached loads; proj is stream-fresh)
        float pc[4], pix[4], pfx[4];
        if (kq == 0) {
#pragma unroll
            for (int r = 0; r < 4; ++r) {
                int b = b0 + mi * 16 + (lane >> 4) * 4 + r;
                int j = j0 + (lane & 15);
                size_t pbase = ((size_t)s * 64 + b) * 6144 + j;
                pc[r] = (float)proj[pbase];
                pix[r] = (float)proj[pbase + 2048];
                pfx[r] = (float)proj[pbase + 4096];
            }
        }

        // A fragments: this wave's 16 rows x 512-k quarter. LLC-bypass loads,
        // issued as one batch, one vmcnt(0) wait (~1 LLC latency).
        half8 afr[16];
        const _Float16* hrow = hcur + (size_t)(b0 + mi * 16 + (lane & 15)) * NH +
                               kq * 512 + (lane >> 4) * 8;
        LLC_LD16(afr[0],  hrow, "0");
        LLC_LD16(afr[1],  hrow, "64");
        LLC_LD16(afr[2],  hrow, "128");
        LLC_LD16(afr[3],  hrow, "192");
        LLC_LD16(afr[4],  hrow, "256");
        LLC_LD16(afr[5],  hrow, "320");
        LLC_LD16(afr[6],  hrow, "384");
        LLC_LD16(afr[7],  hrow, "448");
        LLC_LD16(afr[8],  hrow, "512");
        LLC_LD16(afr[9],  hrow, "576");
        LLC_LD16(afr[10], hrow, "640");
        LLC_LD16(afr[11], hrow, "704");
        LLC_LD16(afr[12], hrow, "768");
        LLC_LD16(afr[13], hrow, "832");
        LLC_LD16(afr[14], hrow, "896");
        LLC_LD16(afr[15], hrow, "960");
        wait_vm0();
        __builtin_amdgcn_sched_barrier(0);   // rule #18: keep MFMA below the wait

        f32x4 ai0 = {}, ai1 = {}, af0 = {}, af1 = {};
#pragma unroll
        for (int u = 0; u < 16; ++u) {
            int fk = kq * 16 + u;
            half8 wi = *(const half8*)(Wlds + ((size_t)fk * 64 + lane) * 8);
            half8 wf = *(const half8*)(Wlds + ((size_t)(64 + fk) * 64 + lane) * 8);
            if (u & 1) {
                ai1 = __builtin_amdgcn_mfma_f32_16x16x32_f16(afr[u], wi, ai1, 0, 0, 0);
                af1 = __builtin_amdgcn_mfma_f32_16x16x32_f16(afr[u], wf, af1, 0, 0, 0);
            } else {
                ai0 = __builtin_amdgcn_mfma_f32_16x16x32_f16(afr[u], wi, ai0, 0, 0, 0);
                af0 = __builtin_amdgcn_mfma_f32_16x16x32_f16(afr[u], wf, af0, 0, 0, 0);
            }
        }
        f32x4 acc_i = ai0 + ai1;
        f32x4 acc_f = af0 + af1;

        if (kq != 0) {
            f32x4* slot = (f32x4*)(red + ((size_t)(mi * 3 + (kq - 1)) * 64 + lane) * 8);
            slot[0] = acc_i;
            slot[1] = acc_f;
        }
        __syncthreads();

        if (kq == 0) {
#pragma unroll
            for (int p = 0; p < 3; ++p) {
                f32x4* slot = (f32x4*)(red + ((size_t)(mi * 3 + p) * 64 + lane) * 8);
                acc_i += slot[0];
                acc_f += slot[1];
            }
#pragma unroll
            for (int r = 0; r < 4; ++r) {
                int b = b0 + mi * 16 + (lane >> 4) * 4 + r;
                int j = j0 + (lane & 15);
                float iv = 1.0f / (1.0f + __expf(-(acc_i[r] + pix[r] + bi_s)));
                float fv = 1.0f / (1.0f + __expf(-(acc_f[r] + pfx[r] + bf_s)));
                float z = iv * pc[r] + fv * hprev[r];
                float hn = 1.0f - 2.0f / (__expf(2.0f * z) + 1.0f);   // tanh(z)
                hprev[r] = hn;
                _Float16 hn16 = (_Float16)hn;
                LLC_ST2(hnxt + (size_t)b * NH + j, hn16);             // -> LLC
                out[(size_t)t * (BATCH * NH) + (size_t)b * NH + j] = hn;
                if (t == T_SEQ - 1)
                    out[(size_t)T_SEQ * (BATCH * NH) + (size_t)b * NH + j] = hn;
            }
        }
        // Per-wave vmcnt(0)+barrier: all waves' bypass stores are complete at
        // the LLC (the coherence point) once every wave passes this barrier.
        __syncthreads();

        if (tid == 0) {
            // Relaxed arrive + relaxed spin: no wbl2/inv. h data already at LLC.
            __hip_atomic_fetch_add(cnt_g, 1u, __ATOMIC_RELAXED, __HIP_MEMORY_SCOPE_AGENT);
            const unsigned target = 128u * (unsigned)(t + 1);
            while (__hip_atomic_load(cnt_g, __ATOMIC_RELAXED, __HIP_MEMORY_SCOPE_AGENT) < target)
                __builtin_amdgcn_s_sleep(2);
        }
        __syncthreads();
    }
}

// ---------------- host launch -----------------------------------------------
extern "C" void kernel_launch(void* const* d_in, const int* in_sizes, int n_in,
                              void* d_out, int out_size, void* d_ws, size_t ws_size,
                              hipStream_t stream) {
    const float* x = (const float*)d_in[0];
    const float* hidden = (const float*)d_in[1];
    const float* W_cx = (const float*)d_in[2];
    const float* W_ih = (const float*)d_in[3];
    const float* W_ix = (const float*)d_in[4];
    const float* W_fh = (const float*)d_in[5];
    const float* W_fx = (const float*)d_in[6];
    const float* b_i = (const float*)d_in[7];
    const float* b_f = (const float*)d_in[8];
    float* out = (float*)d_out;

    char* ws = (char*)d_ws;
    size_t off = 0;
    auto alloc = [&](size_t bytes) {
        char* p = ws + off;
        off += (bytes + 255) & ~(size_t)255;
        return p;
    };
    _Float16* Wp = (_Float16*)alloc((size_t)6144 * NH * 2);       // 24 MB
    _Float16* Wr = (_Float16*)alloc((size_t)2 * NH * NH * 2);     // 16 MB
    _Float16* hb0 = (_Float16*)alloc((size_t)BATCH * NH * 2);
    _Float16* hb1 = (_Float16*)alloc((size_t)BATCH * NH * 2);
    unsigned* cnt = (unsigned*)alloc(256);
    const size_t fixed = off;

    int chunk = 32;
    for (int c = T_SEQ; c >= 32; c >>= 1) {
        size_t need = fixed + (size_t)c * 64 * NH * 2 + (size_t)c * 64 * 6144 * 2 + 1024;
        if (need <= ws_size) { chunk = c; break; }
    }
    _Float16* xh = (_Float16*)alloc((size_t)chunk * 64 * NH * 2);
    _Float16* proj = (_Float16*)alloc((size_t)chunk * 64 * 6144 * 2);

    hipMemsetAsync(cnt, 0, 256, stream);

    const long long wsz = (long long)NH * NH;
    cvt_f32_f16<<<2048, 256, 0, stream>>>(W_cx, Wp, wsz);
    cvt_f32_f16<<<2048, 256, 0, stream>>>(W_ix, Wp + wsz, wsz);
    cvt_f32_f16<<<2048, 256, 0, stream>>>(W_fx, Wp + 2 * wsz, wsz);
    cvt_f32_f16<<<2048, 256, 0, stream>>>(W_ih, Wr, wsz);
    cvt_f32_f16<<<2048, 256, 0, stream>>>(W_fh, Wr + wsz, wsz);
    cvt_f32_f16<<<128, 256, 0, stream>>>(hidden, hb0, (long long)BATCH * NH);

    const int nch = T_SEQ / chunk;
    for (int c = 0; c < nch; ++c) {
        const int t0 = c * chunk;
        const int M = chunk * 64;
        cvt_f32_f16<<<2048, 256, 0, stream>>>(x + (size_t)t0 * 64 * NH, xh, (long long)M * NH);
        proj_gemm<<<dim3((M / 128) * 48), 256, 0, stream>>>(xh, Wp, proj, M);
        scan_kernel<<<256, 512, 143360, stream>>>(proj, Wr, hb0, hb1, b_i, b_f,
                                                  out, cnt, t0, chunk);
    }
}

// Round 3
// 9485.892 us; speedup vs baseline: 2.7269x; 1.4014x over previous
//
#include <hip/hip_runtime.h>
#include <cstdint>
#include <cstddef>

#define T_SEQ 1024
#define BATCH 64
#define NH 2048
// NINP == 2048 as well

typedef _Float16 half8 __attribute__((ext_vector_type(8)));
typedef _Float16 half4 __attribute__((ext_vector_type(4)));
typedef float f32x4 __attribute__((ext_vector_type(4)));
typedef unsigned u32x2 __attribute__((ext_vector_type(2)));

__device__ inline void gload_lds16(const void* g, void* l) {
    __builtin_amdgcn_global_load_lds(
        (const __attribute__((address_space(1))) uint32_t*)g,
        (__attribute__((address_space(3))) uint32_t*)l,
        16, 0, 0);
}

// LLC-bypass 16B load with compile-time byte offset (sc0 sc1: skip L1+L2,
// read at the coherence point = Infinity Cache).
#define LLC_LD16(dst, base, OFFSTR)                                         \
    asm volatile("global_load_dwordx4 %0, %1, off offset:" OFFSTR " sc0 sc1" \
                 : "=v"(dst) : "v"(base))

// LLC-bypass 2B store (write-through to the coherence point).
#define LLC_ST2(addr, val)                                                   \
    asm volatile("global_store_short %0, %1, off sc0 sc1"                    \
                 :: "v"(addr), "v"(val) : "memory")

// LLC-bypass 4B store / 8B load for the flag barrier.
#define LLC_ST4(addr, val)                                                   \
    asm volatile("global_store_dword %0, %1, off sc0 sc1"                    \
                 :: "v"(addr), "v"(val) : "memory")
#define LLC_LD8(dst, addr)                                                   \
    asm volatile("global_load_dwordx2 %0, %1, off sc0 sc1\n\ts_waitcnt vmcnt(0)" \
                 : "=v"(dst) : "v"(addr))

__device__ inline void wait_vm0() {
    asm volatile("s_waitcnt vmcnt(0)" ::: "memory");
}

// ---------------- fp32 -> fp16 conversion (vectorized, n % 4 == 0) ----------
__global__ __launch_bounds__(256) void cvt_f32_f16(const float* __restrict__ src,
                                                   _Float16* __restrict__ dst,
                                                   long long n) {
    long long i = ((long long)blockIdx.x * 256 + threadIdx.x) * 4;
    long long stride = (long long)gridDim.x * 256 * 4;
    for (; i < n; i += stride) {
        const float4 v = *(const float4*)(src + i);
        half4 o;
        o[0] = (_Float16)v.x; o[1] = (_Float16)v.y;
        o[2] = (_Float16)v.z; o[3] = (_Float16)v.w;
        *(half4*)(dst + i) = o;
    }
}

// ---------------- projection GEMM: C[m][n] = sum_k A[m][k] * B[n][k] --------
// A: [M][2048] fp16, B: [6144][2048] fp16 (Wcx|Wix|Wfx rows), C: [M][6144] fp16
__global__ __launch_bounds__(256) void proj_gemm(const _Float16* __restrict__ A,
                                                 const _Float16* __restrict__ B,
                                                 _Float16* __restrict__ C, int M) {
    __shared__ _Float16 As[128][64];
    __shared__ _Float16 Bs[128][64];
    const int NBN = 48;                 // 6144 / 128
    const int nbm = M >> 7;
    const int nwg = nbm * NBN;          // divisible by 8 (M >= 2048)
    const int per = nwg >> 3;
    const int bid = blockIdx.x;
    const int swz = (bid & 7) * per + (bid >> 3);   // XCD-aware swizzle (bijective)
    const int bm = swz / NBN, bn = swz % NBN;

    const int tid = threadIdx.x;
    const int lane = tid & 63, w = tid >> 6;
    const int wm = w & 1, wn = w >> 1;

    f32x4 acc[4][4] = {};

    const int srow = lane >> 3;         // 0..7
    const int scol = (lane & 7) * 8;    // half units

    for (int bk = 0; bk < NH / 64; ++bk) {
#pragma unroll
        for (int i = 0; i < 4; ++i) {
            int r = w * 32 + i * 8;
            const _Float16* gA = A + (size_t)(bm * 128 + r + srow) * NH + bk * 64 + scol;
            gload_lds16(gA, &As[r][0]);
            const _Float16* gB = B + (size_t)(bn * 128 + r + srow) * NH + bk * 64 + scol;
            gload_lds16(gB, &Bs[r][0]);
        }
        __syncthreads();
#pragma unroll
        for (int kk = 0; kk < 2; ++kk) {
            half8 af[4], bf[4];
#pragma unroll
            for (int mi = 0; mi < 4; ++mi)
                af[mi] = *(const half8*)&As[wm * 64 + mi * 16 + (lane & 15)][kk * 32 + (lane >> 4) * 8];
#pragma unroll
            for (int ni = 0; ni < 4; ++ni)
                bf[ni] = *(const half8*)&Bs[wn * 64 + ni * 16 + (lane & 15)][kk * 32 + (lane >> 4) * 8];
#pragma unroll
            for (int mi = 0; mi < 4; ++mi)
#pragma unroll
                for (int ni = 0; ni < 4; ++ni)
                    acc[mi][ni] = __builtin_amdgcn_mfma_f32_16x16x32_f16(af[mi], bf[ni], acc[mi][ni], 0, 0, 0);
        }
        __syncthreads();
    }
#pragma unroll
    for (int mi = 0; mi < 4; ++mi)
#pragma unroll
        for (int ni = 0; ni < 4; ++ni)
#pragma unroll
            for (int r = 0; r < 4; ++r) {
                int m = bm * 128 + wm * 64 + mi * 16 + (lane >> 4) * 4 + r;
                int n = bn * 128 + wn * 64 + ni * 16 + (lane & 15);
                C[(size_t)m * 6144 + n] = (_Float16)acc[mi][ni][r];
            }
}

// ---------------- persistent scan kernel ------------------------------------
// 256 WGs x 512 threads, 1 WG/CU (LDS-forced). Each WG: b-group g (32 rows),
// j-slice of 16 columns (XCD-contiguous). Weights (128KB) in LDS in MFMA
// B-fragment order. Cross-step h goes through the Infinity Cache (sc0 sc1
// bypass). Barrier: per-WG flag STORES (no RMW) + each WG's wave 0 polls all
// 128 flags of its group. Two independent barriers (one per b-group).
__global__ __launch_bounds__(512, 1) void scan_kernel(
    const _Float16* __restrict__ proj,   // [nsteps*64][6144] fp16 (c | ix | fx)
    const _Float16* __restrict__ Wr,     // [2][2048][2048] fp16 (W_ih, W_fh)
    _Float16* hb0, _Float16* hb1,        // [64][2048] fp16 ping-pong
    const float* __restrict__ b_i, const float* __restrict__ b_f,
    float* __restrict__ out,             // d_out: [1024][64][2048] + [64][2048]
    unsigned* flags, int t0, int nsteps) {
    extern __shared__ char smem[];
    _Float16* Wlds = (_Float16*)smem;          // 131072 B
    float* red = (float*)(smem + 131072);      // 12288 B

    // XCD-contiguous mapping: wg%8 = XCD (round-robin dispatch); give each XCD
    // 16 contiguous j-slices per group so proj/out 128B lines stay on one XCD.
    const int wg = blockIdx.x;
    const int xcd = wg & 7;
    const int slot = wg >> 3;            // 0..31
    const int g = slot & 1;              // b-group
    const int idx = xcd * 16 + (slot >> 1);   // 0..127, contiguous per XCD
    const int j0 = idx * 16;
    const int b0 = g * 32;
    unsigned* flags_g = flags + g * 256;      // 1KB apart per group

    const int tid = threadIdx.x;
    const int lane = tid & 63;
    const int w = tid >> 6;      // 8 waves
    const int mi = w & 1;        // m-tile (16 rows)
    const int kq = w >> 1;       // k-quarter (512 k)

    // One-time fill of LDS weight fragments:
    // fragment (gate, kk 0..63, lane l) = W[j0 + (l&15)][kk*32 + (l>>4)*8 .. +8]
    for (int q = 0; q < 16; ++q) {
        int e = q * 512 + tid;            // 0..8191
        int l = e & 63;
        int fk = (e >> 6) & 63;
        int gate = e >> 12;
        const _Float16* src = Wr + ((size_t)gate << 22) +
                              (size_t)(j0 + (l & 15)) * NH + fk * 32 + (l >> 4) * 8;
        *(half8*)(Wlds + ((size_t)(gate * 64 + fk) * 64 + l) * 8) = *(const half8*)src;
    }

    const float bi_s = b_i[j0 + (lane & 15)];
    const float bf_s = b_f[j0 + (lane & 15)];

    // h[b][j] carry + first-step proj preload (epilogue waves only).
    float hprev[4], pc[4], pix[4], pfx[4];
    if (kq == 0) {
        const _Float16* hini = (t0 & 1) ? hb1 : hb0;
#pragma unroll
        for (int r = 0; r < 4; ++r) {
            int b = b0 + mi * 16 + (lane >> 4) * 4 + r;
            int j = j0 + (lane & 15);
            unsigned tmp;
            asm volatile("global_load_ushort %0, %1, off sc0 sc1\n\ts_waitcnt vmcnt(0)"
                         : "=v"(tmp) : "v"(hini + (size_t)b * NH + j));
            hprev[r] = (float)__builtin_bit_cast(_Float16, (unsigned short)tmp);
            size_t pbase = ((size_t)b) * 6144 + j;
            pc[r] = (float)proj[pbase];
            pix[r] = (float)proj[pbase + 2048];
            pfx[r] = (float)proj[pbase + 4096];
        }
    }

    __syncthreads();

    for (int s = 0; s < nsteps; ++s) {
        const int t = t0 + s;
        const _Float16* hcur = (t & 1) ? hb1 : hb0;
        _Float16* hnxt = (t & 1) ? hb0 : hb1;

        // A fragments: this wave's 16 rows x 512-k quarter. LLC-bypass loads,
        // issued as one batch, one vmcnt(0) wait (~1 LLC latency).
        half8 afr[16];
        const _Float16* hrow = hcur + (size_t)(b0 + mi * 16 + (lane & 15)) * NH +
                               kq * 512 + (lane >> 4) * 8;
        LLC_LD16(afr[0],  hrow, "0");
        LLC_LD16(afr[1],  hrow, "64");
        LLC_LD16(afr[2],  hrow, "128");
        LLC_LD16(afr[3],  hrow, "192");
        LLC_LD16(afr[4],  hrow, "256");
        LLC_LD16(afr[5],  hrow, "320");
        LLC_LD16(afr[6],  hrow, "384");
        LLC_LD16(afr[7],  hrow, "448");
        LLC_LD16(afr[8],  hrow, "512");
        LLC_LD16(afr[9],  hrow, "576");
        LLC_LD16(afr[10], hrow, "640");
        LLC_LD16(afr[11], hrow, "704");
        LLC_LD16(afr[12], hrow, "768");
        LLC_LD16(afr[13], hrow, "832");
        LLC_LD16(afr[14], hrow, "896");
        LLC_LD16(afr[15], hrow, "960");
        wait_vm0();
        __builtin_amdgcn_sched_barrier(0);   // rule #18: keep MFMA below the wait

        f32x4 ai0 = {}, ai1 = {}, af0 = {}, af1 = {};
#pragma unroll
        for (int u = 0; u < 16; ++u) {
            int fk = kq * 16 + u;
            half8 wi = *(const half8*)(Wlds + ((size_t)fk * 64 + lane) * 8);
            half8 wf = *(const half8*)(Wlds + ((size_t)(64 + fk) * 64 + lane) * 8);
            if (u & 1) {
                ai1 = __builtin_amdgcn_mfma_f32_16x16x32_f16(afr[u], wi, ai1, 0, 0, 0);
                af1 = __builtin_amdgcn_mfma_f32_16x16x32_f16(afr[u], wf, af1, 0, 0, 0);
            } else {
                ai0 = __builtin_amdgcn_mfma_f32_16x16x32_f16(afr[u], wi, ai0, 0, 0, 0);
                af0 = __builtin_amdgcn_mfma_f32_16x16x32_f16(afr[u], wf, af0, 0, 0, 0);
            }
        }
        f32x4 acc_i = ai0 + ai1;
        f32x4 acc_f = af0 + af1;

        if (kq != 0) {
            f32x4* slot_p = (f32x4*)(red + ((size_t)(mi * 3 + (kq - 1)) * 64 + lane) * 8);
            slot_p[0] = acc_i;
            slot_p[1] = acc_f;
        }
        __syncthreads();

        float hn_keep[4];
        if (kq == 0) {
#pragma unroll
            for (int p = 0; p < 3; ++p) {
                f32x4* slot_p = (f32x4*)(red + ((size_t)(mi * 3 + p) * 64 + lane) * 8);
                acc_i += slot_p[0];
                acc_f += slot_p[1];
            }
#pragma unroll
            for (int r = 0; r < 4; ++r) {
                int b = b0 + mi * 16 + (lane >> 4) * 4 + r;
                int j = j0 + (lane & 15);
                float iv = 1.0f / (1.0f + __expf(-(acc_i[r] + pix[r] + bi_s)));
                float fv = 1.0f / (1.0f + __expf(-(acc_f[r] + pfx[r] + bf_s)));
                float z = iv * pc[r] + fv * hprev[r];
                float hn = 1.0f - 2.0f / (__expf(2.0f * z) + 1.0f);   // tanh(z)
                hprev[r] = hn;
                hn_keep[r] = hn;
                _Float16 hn16 = (_Float16)hn;
                LLC_ST2(hnxt + (size_t)b * NH + j, hn16);             // -> LLC
            }
        }
        // Drains the h-stores (per-wave vmcnt(0) before s_barrier): once every
        // wave passes, all h values for this WG are complete at the LLC.
        __syncthreads();

        const unsigned tv = (unsigned)(t + 1);
        // Arrive: one flag STORE per WG (distinct addresses -> no RMW serial).
        if (tid == 0) {
            unsigned* myflag = flags_g + idx;
            LLC_ST4(myflag, tv);
        }
        // out-stores: issued after arrive; they complete during the poll.
        if (kq == 0) {
#pragma unroll
            for (int r = 0; r < 4; ++r) {
                int b = b0 + mi * 16 + (lane >> 4) * 4 + r;
                int j = j0 + (lane & 15);
                out[(size_t)t * (BATCH * NH) + (size_t)b * NH + j] = hn_keep[r];
                if (t == T_SEQ - 1)
                    out[(size_t)T_SEQ * (BATCH * NH) + (size_t)b * NH + j] = hn_keep[r];
            }
            // proj prefetch for next step (consumed after the barrier).
            if (s + 1 < nsteps) {
#pragma unroll
                for (int r = 0; r < 4; ++r) {
                    int b = b0 + mi * 16 + (lane >> 4) * 4 + r;
                    int j = j0 + (lane & 15);
                    size_t pbase = ((size_t)(s + 1) * 64 + b) * 6144 + j;
                    pc[r] = (float)proj[pbase];
                    pix[r] = (float)proj[pbase + 2048];
                    pfx[r] = (float)proj[pbase + 4096];
                }
            }
        }
        // Wave 0 polls all 128 flags of its group (4 cache lines, 2 per lane).
        if (w == 0) {
            const unsigned* fb = flags_g + lane * 2;
            while (true) {
                u32x2 v;
                LLC_LD8(v, fb);
                if (__all(v[0] >= tv && v[1] >= tv)) break;
                __builtin_amdgcn_s_sleep(1);
            }
        }
        __syncthreads();
    }
}

// ---------------- host launch -----------------------------------------------
extern "C" void kernel_launch(void* const* d_in, const int* in_sizes, int n_in,
                              void* d_out, int out_size, void* d_ws, size_t ws_size,
                              hipStream_t stream) {
    const float* x = (const float*)d_in[0];
    const float* hidden = (const float*)d_in[1];
    const float* W_cx = (const float*)d_in[2];
    const float* W_ih = (const float*)d_in[3];
    const float* W_ix = (const float*)d_in[4];
    const float* W_fh = (const float*)d_in[5];
    const float* W_fx = (const float*)d_in[6];
    const float* b_i = (const float*)d_in[7];
    const float* b_f = (const float*)d_in[8];
    float* out = (float*)d_out;

    char* ws = (char*)d_ws;
    size_t off = 0;
    auto alloc = [&](size_t bytes) {
        char* p = ws + off;
        off += (bytes + 255) & ~(size_t)255;
        return p;
    };
    _Float16* Wp = (_Float16*)alloc((size_t)6144 * NH * 2);       // 24 MB
    _Float16* Wr = (_Float16*)alloc((size_t)2 * NH * NH * 2);     // 16 MB
    _Float16* hb0 = (_Float16*)alloc((size_t)BATCH * NH * 2);
    _Float16* hb1 = (_Float16*)alloc((size_t)BATCH * NH * 2);
    unsigned* flags = (unsigned*)alloc(4096);
    const size_t fixed = off;

    int chunk = 32;
    for (int c = T_SEQ; c >= 32; c >>= 1) {
        size_t need = fixed + (size_t)c * 64 * NH * 2 + (size_t)c * 64 * 6144 * 2 + 1024;
        if (need <= ws_size) { chunk = c; break; }
    }
    _Float16* xh = (_Float16*)alloc((size_t)chunk * 64 * NH * 2);
    _Float16* proj = (_Float16*)alloc((size_t)chunk * 64 * 6144 * 2);

    hipMemsetAsync(flags, 0, 4096, stream);

    const long long wsz = (long long)NH * NH;
    cvt_f32_f16<<<2048, 256, 0, stream>>>(W_cx, Wp, wsz);
    cvt_f32_f16<<<2048, 256, 0, stream>>>(W_ix, Wp + wsz, wsz);
    cvt_f32_f16<<<2048, 256, 0, stream>>>(W_fx, Wp + 2 * wsz, wsz);
    cvt_f32_f16<<<2048, 256, 0, stream>>>(W_ih, Wr, wsz);
    cvt_f32_f16<<<2048, 256, 0, stream>>>(W_fh, Wr + wsz, wsz);
    cvt_f32_f16<<<128, 256, 0, stream>>>(hidden, hb0, (long long)BATCH * NH);

    const int nch = T_SEQ / chunk;
    for (int c = 0; c < nch; ++c) {
        const int t0 = c * chunk;
        const int M = chunk * 64;
        cvt_f32_f16<<<2048, 256, 0, stream>>>(x + (size_t)t0 * 64 * NH, xh, (long long)M * NH);
        proj_gemm<<<dim3((M / 128) * 48), 256, 0, stream>>>(xh, Wp, proj, M);
        scan_kernel<<<256, 512, 143360, stream>>>(proj, Wr, hb0, hb1, b_i, b_f,
                                                  out, flags, t0, chunk);
    }
}